// Round 8
// baseline (271.326 us; speedup 1.0000x reference)
//
#include <hip/hip_runtime.h>
#include <hip/hip_bf16.h>

// Problem constants
#define P_TOTAL 16384      // H*W pixels
#define KN      16         // kernels per pixel
#define CK      144        // in_channel * kernel_size
#define BATCH   8
#define IMG     262144     // C*H*W
#define PATCH_H 160        // padded patch row length (halfwords); K padded 144->160

typedef __attribute__((ext_vector_type(8))) short bf16x8;   // MFMA A/B frag (4 VGPRs)
typedef __attribute__((ext_vector_type(4))) float f32x4;    // MFMA C/D frag

__device__ __forceinline__ short f2bf(float f) {
    __hip_bfloat16 h = __float2bfloat16(f);
    return *reinterpret_cast<short*>(&h);
}

// ---------- K0: transpose+quantize x[b][id] f32 -> xt[id][b] bf16 (4.19 MB) ----------
__global__ __launch_bounds__(256) void transpose_x_bf16(
    const float* __restrict__ x, float4* __restrict__ xt)
{
    const int i = blockIdx.x * 256 + threadIdx.x;
    union { short h[8]; float4 f4; } u;
#pragma unroll
    for (int b = 0; b < BATCH; ++b)
        u.h[b] = f2bf(x[(size_t)b * IMG + i]);
    xt[i] = u.f4;
}

// ---------- K1a/K1b: gather, temporally halved so each pass's xt half (2.1 MB)
// stays L2-resident per XCD. Kernel boundary = chip-wide phase barrier. ----------
template <int PASS>
__global__ __launch_bounds__(256) void gather_half(
    const float4*   __restrict__ xt,      // bf16 [IMG][8]
    const int*      __restrict__ hidx,    // [P][CK]
    unsigned short* __restrict__ patches) // [P][8][160] bf16
{
    const int t    = threadIdx.x;
    const int wv   = t >> 6;
    const int lane = t & 63;
    const int bid  = blockIdx.x;
    const int p    = (bid & 7) * (P_TOTAL / 8) + (bid >> 3) * 4 + wv;

    const int LO = PASS ? (IMG / 2) : 0;
    const int HI = PASS ? IMG : (IMG / 2);

    const int* hp = hidx + p * CK;
    unsigned short* pp = patches + (size_t)p * BATCH * PATCH_H;

    const bool tail = lane < (CK - 128);           // lanes 0..15 -> c=128..143
    const int id0 = hp[lane];
    const int id1 = hp[lane + 64];
    const int id2 = tail ? hp[lane + 128] : 0;

    union { unsigned short h[8]; float4 f4; } u;
    if (id0 >= LO && id0 < HI) {
        u.f4 = xt[id0];
#pragma unroll
        for (int b = 0; b < BATCH; ++b) pp[b * PATCH_H + lane] = u.h[b];
    }
    if (id1 >= LO && id1 < HI) {
        u.f4 = xt[id1];
#pragma unroll
        for (int b = 0; b < BATCH; ++b) pp[b * PATCH_H + lane + 64] = u.h[b];
    }
    if (tail && id2 >= LO && id2 < HI) {
        u.f4 = xt[id2];
#pragma unroll
        for (int b = 0; b < BATCH; ++b) pp[b * PATCH_H + lane + 128] = u.h[b];
    }
    if (PASS == 0 && !tail && lane < 32) {         // lanes 16..31: zero-pad c=144..159
#pragma unroll
        for (int b = 0; b < BATCH; ++b) pp[b * PATCH_H + lane + 128] = 0;
    }
}

// ---------- K2: pure-streaming GEMM (verified R7). No LDS, no barrier. ----------
__global__ __launch_bounds__(256) void gemm_mfma(
    const unsigned short* __restrict__ patches,  // [P][8][160] bf16
    const float* __restrict__ w,                 // [P][KN][CK] f32
    float* __restrict__ out)                     // [B][KN][P] f32
{
    const int t    = threadIdx.x;
    const int wv   = t >> 6;
    const int lane = t & 63;
    const int bid  = blockIdx.x;
    const int p    = (bid & 7) * (P_TOTAL / 8) + (bid >> 3) * 4 + wv;

    const int n    = lane & 15;      // output k; A-row selector
    const int q    = lane >> 4;      // K-quad
    const int arow = n & 7;          // rows 8-15 broadcast rows 0-7 (dups discarded)
    const unsigned short* ap = patches + (size_t)p * BATCH * PATCH_H + (size_t)arow * PATCH_H;
    const float* wp = w + (size_t)p * (KN * CK) + (size_t)n * CK;

    f32x4 acc = {0.f, 0.f, 0.f, 0.f};
#pragma unroll
    for (int s = 0; s < 5; ++s) {
        const int c = 32 * s + 8 * q;
        bf16x8 a = *reinterpret_cast<const bf16x8*>(ap + c);  // 16B aligned
        bf16x8 b = {0, 0, 0, 0, 0, 0, 0, 0};
        if (c < CK) {                 // s=4,q>=2 -> zero frag (A reads pad zeros)
            const float4 f0 = *reinterpret_cast<const float4*>(wp + c);
            const float4 f1 = *reinterpret_cast<const float4*>(wp + c + 4);
            b[0] = f2bf(f0.x); b[1] = f2bf(f0.y); b[2] = f2bf(f0.z); b[3] = f2bf(f0.w);
            b[4] = f2bf(f1.x); b[5] = f2bf(f1.y); b[6] = f2bf(f1.z); b[7] = f2bf(f1.w);
        }
        acc = __builtin_amdgcn_mfma_f32_16x16x32_bf16(a, b, acc, 0, 0, 0);
    }

    // C/D: col=lane&15 (=k), row=q*4+i (=b); rows 8-15 duplicate rows 0-7
    if (lane < 32) {
#pragma unroll
        for (int i = 0; i < 4; ++i) {
            const int b = q * 4 + i;
            out[(size_t)b * (KN * P_TOTAL) + (size_t)n * P_TOTAL + p] = acc[i];
        }
    }
}

// ---------- fallback (tiny workspace): R2-style single kernel ----------
__global__ __launch_bounds__(256) void abc2d_fallback(
    const float* __restrict__ x, const float* __restrict__ w,
    const int* __restrict__ hidx, float* __restrict__ out)
{
    __shared__ float patch[CK * 12];
    const int bid = blockIdx.x;
    const int p   = (bid & 7) * (P_TOTAL / 8) + (bid >> 3);
    const int t   = threadIdx.x;
    const int* hp = hidx + p * CK;
    for (int j = t; j < CK * BATCH; j += 256) {
        const int c = j >> 3, b = j & 7;
        patch[c * 12 + b] = x[(size_t)hp[c] + (size_t)b * IMG];
    }
    __syncthreads();
    const int k = t >> 4, cs = t & 15;
    const float* wp = w + (size_t)p * (KN * CK) + (size_t)k * CK;
    float acc[BATCH];
#pragma unroll
    for (int b = 0; b < BATCH; ++b) acc[b] = 0.f;
#pragma unroll
    for (int i = 0; i < 9; ++i) {
        const int c = cs + 16 * i;
        const float wv = wp[c];
        const float* pr = &patch[c * 12];
#pragma unroll
        for (int b = 0; b < BATCH; ++b) acc[b] += wv * pr[b];
    }
#pragma unroll
    for (int b = 0; b < BATCH; ++b) {
        float v = acc[b];
        v += __shfl_xor(v, 1); v += __shfl_xor(v, 2);
        v += __shfl_xor(v, 4); v += __shfl_xor(v, 8);
        acc[b] = v;
    }
    if (cs == 0)
#pragma unroll
        for (int b = 0; b < BATCH; ++b)
            out[(size_t)b * (KN * P_TOTAL) + (size_t)k * P_TOTAL + p] = acc[b];
}

extern "C" void kernel_launch(void* const* d_in, const int* in_sizes, int n_in,
                              void* d_out, int out_size, void* d_ws, size_t ws_size,
                              hipStream_t stream) {
    const float* x    = (const float*)d_in[0];   // [8,16,128,128] f32
    const float* wts  = (const float*)d_in[1];   // [16384,16,144] f32
    const int*   hidx = (const int*)d_in[2];     // [16384,144] int32
    float* out = (float*)d_out;                  // [8,16,16384] f32

    const size_t patch_bytes = (size_t)P_TOTAL * BATCH * PATCH_H * sizeof(short); // 41.9 MB
    const size_t patch_off   = 8u << 20;                                          // 8 MB align

    if (ws_size >= patch_off + patch_bytes) {
        float4* xt = (float4*)d_ws;
        unsigned short* patches = (unsigned short*)((char*)d_ws + patch_off);
        transpose_x_bf16<<<IMG / 256, 256, 0, stream>>>(x, xt);
        gather_half<0><<<P_TOTAL / 4, 256, 0, stream>>>(xt, hidx, patches);
        gather_half<1><<<P_TOTAL / 4, 256, 0, stream>>>(xt, hidx, patches);
        gemm_mfma<<<P_TOTAL / 4, 256, 0, stream>>>(patches, wts, out);
    } else {
        abc2d_fallback<<<P_TOTAL, 256, 0, stream>>>(x, wts, hidx, out);
    }
}

// Round 9
// 246.727 us; speedup vs baseline: 1.0997x; 1.0997x over previous
//
#include <hip/hip_runtime.h>
#include <hip/hip_bf16.h>

// Problem constants
#define P_TOTAL 16384      // H*W pixels
#define KN      16         // kernels per pixel
#define CK      144        // in_channel * kernel_size
#define BATCH   8
#define IMG     262144     // C*H*W
#define RWH     176        // patchT row stride in halfwords (88 words, 16B-aligned)

typedef __attribute__((ext_vector_type(8))) short bf16x8;   // MFMA A/B frag (4 VGPRs)
typedef __attribute__((ext_vector_type(4))) float f32x4;    // MFMA C/D frag

__device__ __forceinline__ short f2bf(float f) {
    __hip_bfloat16 h = __float2bfloat16(f);
    return *reinterpret_cast<short*>(&h);
}

// ---------- K0: transpose+quantize x[b][id] f32 -> xt[id][b] bf16 (4.19 MB) ----------
__global__ __launch_bounds__(256) void transpose_x_bf16(
    const float* __restrict__ x, float4* __restrict__ xt)
{
    const int i = blockIdx.x * 256 + threadIdx.x;
    union { short h[8]; float4 f4; } u;
#pragma unroll
    for (int b = 0; b < BATCH; ++b)
        u.h[b] = f2bf(x[(size_t)b * IMG + i]);
    xt[i] = u.f4;
}

// ---------- fused main: 2 pixels per wave for 2.7x gather MLP ----------
// Per lane: 6 independent hidx loads, then 6 independent random 16B xt loads,
// all in flight before any consumer. Wave-private LDS segments -> no barrier.
__global__ __launch_bounds__(256) void abc2d_fused2(
    const float4* __restrict__ xt,    // bf16 [IMG][8]
    const float*  __restrict__ w,     // [P][KN][CK] f32
    const int*    __restrict__ hidx,  // [P][CK]
    float* __restrict__ out)          // [B][KN][P] f32
{
    __shared__ short patchT[4 * 2 * 8 * RWH];   // 4 waves x 2 pix x 8 rows x 176 = 22528 B

    const int t    = threadIdx.x;
    const int wv   = t >> 6;
    const int lane = t & 63;
    const int bid  = blockIdx.x;                 // [0, 2048)
    // XCD swizzle: XCD x owns p in [x*2048,(x+1)*2048)
    const int pb   = (bid & 7) * 2048 + (bid >> 3) * 8 + wv * 2;   // wave's pixel pair

    short* pT0 = patchT + wv * (2 * 8 * RWH);
    short* pT1 = pT0 + 8 * RWH;

    // ---------- gather: all index loads, then all data loads (MLP ~4.5/lane) ----------
    const int* hp0 = hidx + (size_t)pb * CK;
    const int* hp1 = hp0 + CK;
    const bool tail = lane < (CK - 128);         // lanes 0..15 -> c=128..143
    const int i00 = hp0[lane];
    const int i01 = hp0[lane + 64];
    const int i10 = hp1[lane];
    const int i11 = hp1[lane + 64];
    const int i02 = tail ? hp0[lane + 128] : 0;
    const int i12 = tail ? hp1[lane + 128] : 0;

    union U { unsigned short h[8]; float4 f4; };
    U u00, u01, u02, u10, u11, u12;
    u00.f4 = xt[i00];
    u01.f4 = xt[i01];
    u10.f4 = xt[i10];
    u11.f4 = xt[i11];
    if (tail) { u02.f4 = xt[i02]; u12.f4 = xt[i12]; }

    // b16 scatter to LDS (2 lanes/bank = free)
#pragma unroll
    for (int b = 0; b < BATCH; ++b) {
        pT0[b * RWH + lane]      = (short)u00.h[b];
        pT0[b * RWH + lane + 64] = (short)u01.h[b];
        pT1[b * RWH + lane]      = (short)u10.h[b];
        pT1[b * RWH + lane + 64] = (short)u11.h[b];
    }
    if (tail) {
#pragma unroll
        for (int b = 0; b < BATCH; ++b) {
            pT0[b * RWH + lane + 128] = (short)u02.h[b];
            pT1[b * RWH + lane + 128] = (short)u12.h[b];
        }
    }
    // zero-pad c=144..159 (words 72..79 of each 88-word row), one b32/lane/pixel
    {
        const int r = lane >> 3, wd = lane & 7;
        reinterpret_cast<int*>(pT0)[r * 88 + 72 + wd] = 0;
        reinterpret_cast<int*>(pT1)[r * 88 + 72 + wd] = 0;
    }

    // ---------- MFMA compute, 2 pixels (wave-internal LDS dep; no barrier) ----------
    const int n    = lane & 15;      // output k
    const int q    = lane >> 4;      // K-quad
    const int arow = n & 7;          // rows 8-15 broadcast rows 0-7 (dups discarded)

#pragma unroll
    for (int pp = 0; pp < 2; ++pp) {
        const short* ap = (pp ? pT1 : pT0) + arow * RWH;
        const float* wp = w + (size_t)(pb + pp) * (KN * CK) + (size_t)n * CK;

        f32x4 acc = {0.f, 0.f, 0.f, 0.f};
#pragma unroll
        for (int s = 0; s < 5; ++s) {
            const int c = 32 * s + 8 * q;
            bf16x8 a = *reinterpret_cast<const bf16x8*>(ap + c);   // 16B aligned
            bf16x8 b = {0, 0, 0, 0, 0, 0, 0, 0};
            if (c < CK) {             // s=4,q>=2 -> zero frag (A reads pad zeros)
                const float4 f0 = *reinterpret_cast<const float4*>(wp + c);
                const float4 f1 = *reinterpret_cast<const float4*>(wp + c + 4);
                b[0] = f2bf(f0.x); b[1] = f2bf(f0.y); b[2] = f2bf(f0.z); b[3] = f2bf(f0.w);
                b[4] = f2bf(f1.x); b[5] = f2bf(f1.y); b[6] = f2bf(f1.z); b[7] = f2bf(f1.w);
            }
            acc = __builtin_amdgcn_mfma_f32_16x16x32_bf16(a, b, acc, 0, 0, 0);
        }

        // C/D: col=lane&15 (=k), row=q*4+i (=b); rows 8-15 duplicate rows 0-7
        if (lane < 32) {
#pragma unroll
            for (int i = 0; i < 4; ++i) {
                const int b = q * 4 + i;
                out[(size_t)b * (KN * P_TOTAL) + (size_t)n * P_TOTAL + (pb + pp)] = acc[i];
            }
        }
    }
}

// ---------- fallback (tiny workspace): R2-style single kernel ----------
__global__ __launch_bounds__(256) void abc2d_fallback(
    const float* __restrict__ x, const float* __restrict__ w,
    const int* __restrict__ hidx, float* __restrict__ out)
{
    __shared__ float patch[CK * 12];
    const int bid = blockIdx.x;
    const int p   = (bid & 7) * (P_TOTAL / 8) + (bid >> 3);
    const int t   = threadIdx.x;
    const int* hp = hidx + p * CK;
    for (int j = t; j < CK * BATCH; j += 256) {
        const int c = j >> 3, b = j & 7;
        patch[c * 12 + b] = x[(size_t)hp[c] + (size_t)b * IMG];
    }
    __syncthreads();
    const int k = t >> 4, cs = t & 15;
    const float* wp = w + (size_t)p * (KN * CK) + (size_t)k * CK;
    float acc[BATCH];
#pragma unroll
    for (int b = 0; b < BATCH; ++b) acc[b] = 0.f;
#pragma unroll
    for (int i = 0; i < 9; ++i) {
        const int c = cs + 16 * i;
        const float wv = wp[c];
        const float* pr = &patch[c * 12];
#pragma unroll
        for (int b = 0; b < BATCH; ++b) acc[b] += wv * pr[b];
    }
#pragma unroll
    for (int b = 0; b < BATCH; ++b) {
        float v = acc[b];
        v += __shfl_xor(v, 1); v += __shfl_xor(v, 2);
        v += __shfl_xor(v, 4); v += __shfl_xor(v, 8);
        acc[b] = v;
    }
    if (cs == 0)
#pragma unroll
        for (int b = 0; b < BATCH; ++b)
            out[(size_t)b * (KN * P_TOTAL) + (size_t)k * P_TOTAL + p] = acc[b];
}

extern "C" void kernel_launch(void* const* d_in, const int* in_sizes, int n_in,
                              void* d_out, int out_size, void* d_ws, size_t ws_size,
                              hipStream_t stream) {
    const float* x    = (const float*)d_in[0];   // [8,16,128,128] f32
    const float* wts  = (const float*)d_in[1];   // [16384,16,144] f32
    const int*   hidx = (const int*)d_in[2];     // [16384,144] int32
    float* out = (float*)d_out;                  // [8,16,16384] f32

    const size_t xt_bytes = (size_t)IMG * BATCH * sizeof(short);   // 4.19 MB
    if (ws_size >= xt_bytes) {
        float4* xt = (float4*)d_ws;
        transpose_x_bf16<<<IMG / 256, 256, 0, stream>>>(x, xt);
        abc2d_fused2<<<P_TOTAL / 8, 256, 0, stream>>>(xt, wts, hidx, out);
    } else {
        abc2d_fallback<<<P_TOTAL, 256, 0, stream>>>(x, wts, hidx, out);
    }
}